// Round 1
// baseline (1141.456 us; speedup 1.0000x reference)
//
#include <hip/hip_runtime.h>
#include <math.h>

#define NPIX 4096

__device__ __forceinline__ float wave_sum(float v) {
#pragma unroll
  for (int m = 32; m >= 1; m >>= 1) v += __shfl_xor(v, m, 64);
  return v;
}

__device__ __forceinline__ float lin_(int i) { return -1.f + (2.f * (float)i) / 63.f; }

// ---------------- init: broadcast slots_p, clip s_pos/s_scale ----------------
__global__ __launch_bounds__(256) void k_init(const float* __restrict__ slots_p,
    const float* __restrict__ s_pos_p, const float* __restrict__ s_scale_p,
    float* __restrict__ slotsS, float* __restrict__ sposS, float* __restrict__ sscaleS) {
  int i = blockIdx.x * 256 + threadIdx.x;
  if (i < 8 * 8 * 64) slotsS[i] = slots_p[i & 511];
  if (i < 8 * 8 * 2) {
    float p = s_pos_p[i & 15];
    sposS[i] = fminf(fmaxf(p, -1.f), 1.f);
    float sc = s_scale_p[i & 15];
    sscaleS[i] = fminf(fmaxf(sc, 0.001f), 2.f);
  }
}

// ---------------- precompute: x = ln(inputs); k0 = x@Wk+bk; v0 = x@Wv+bv ----
__global__ __launch_bounds__(256) void k_pre(const float* __restrict__ inp,
    const float* __restrict__ g_in, const float* __restrict__ b_in,
    const float* __restrict__ Wk, const float* __restrict__ bk,
    const float* __restrict__ Wv, const float* __restrict__ bv,
    float* __restrict__ k0, float* __restrict__ v0) {
  int w = threadIdx.x >> 6, lane = threadIdx.x & 63;
  int p = blockIdx.x * 4 + w;  // 0..32767 = B*N
  float v = inp[(size_t)p * 64 + lane];
  float m = wave_sum(v) * 0.015625f;
  float c = v - m;
  float var = wave_sum(c * c) * 0.015625f;
  float x = c * rsqrtf(var + 1e-5f) * g_in[lane] + b_in[lane];
  __shared__ float xs[4][64];
  xs[w][lane] = x;
  __syncthreads();
  float ak = bk[lane], av = bv[lane];
#pragma unroll
  for (int d = 0; d < 64; ++d) {
    float xv = xs[w][d];
    ak += xv * Wk[d * 64 + lane];
    av += xv * Wv[d * 64 + lane];
  }
  k0[(size_t)p * 64 + lane] = ak;
  v0[(size_t)p * 64 + lane] = av;
}

// ---------------- per-iter: q = ln(slots)@Wq+bq ; w2q = W2@q ; b2q = b2.q ---
__global__ __launch_bounds__(128) void k_q(
    const float* __restrict__ slotsS, const float* __restrict__ g_slots,
    const float* __restrict__ b_slots, const float* __restrict__ Wq,
    const float* __restrict__ bq, const float* __restrict__ W2,
    const float* __restrict__ b2, float* __restrict__ w2qg, float* __restrict__ b2qg) {
  const int bs = blockIdx.x;
  const int t = threadIdx.x;
  __shared__ float xn[64], qsh[64];
  if (t < 64) {
    float v = slotsS[bs * 64 + t];
    float m = wave_sum(v) * 0.015625f;
    float c = v - m;
    float var = wave_sum(c * c) * 0.015625f;
    xn[t] = c * rsqrtf(var + 1e-5f) * g_slots[t] + b_slots[t];
  }
  __syncthreads();
  if (t < 64) {
    float a = bq[t];
#pragma unroll
    for (int d = 0; d < 64; ++d) a += xn[d] * Wq[d * 64 + t];
    qsh[t] = a;
  }
  __syncthreads();
  {
    float a = 0.f;
#pragma unroll
    for (int d = 0; d < 64; ++d) a += W2[t * 64 + d] * qsh[d];
    w2qg[bs * 128 + t] = a;
  }
  if (t < 64) {
    float p = wave_sum(b2[t] * qsh[t]);
    if (t == 0) b2qg[bs] = p;
  }
}

// ---------------- the big MLP pass (kk->dots, or vv->Hsum) -------------------
// block: 256 thr = 4 waves; each wave does 32 pixels (4 at a time) for one (b,s)
template <bool UPD>
__global__ __launch_bounds__(256) void proj_pass(
    const float* __restrict__ base, const float* __restrict__ W_pos,
    const float* __restrict__ b_pos, const float* __restrict__ gln,
    const float* __restrict__ bln, const float* __restrict__ W1,
    const float* __restrict__ b1, const float* __restrict__ w2q,
    const float* __restrict__ b2q, const float* __restrict__ attn,
    float* __restrict__ Hsum, const float* __restrict__ sposS,
    const float* __restrict__ sscaleS, float* __restrict__ dots) {
  __shared__ float W1p[64 * 128];   // paired: [d*128 + 2k] = W1[d,k], [.. +1] = W1[d,k+64]
  __shared__ float w2qs[128];
  __shared__ float tks[4][4][64];
  const int bs = blockIdx.x;        // b*8+s
  const int tile = blockIdx.y;      // 0..31
  const int b = bs >> 3;
  const int tid = threadIdx.x;
  const int wv = tid >> 6, lane = tid & 63;
  for (int idx = tid; idx < 64 * 128; idx += 256) {
    int d = idx >> 7, k = idx & 127;
    int pos = (k < 64) ? (d * 128 + 2 * k) : (d * 128 + 2 * (k - 64) + 1);
    W1p[pos] = W1[idx];
  }
  if (!UPD && tid < 128) w2qs[tid] = w2q[bs * 128 + tid];
  __syncthreads();
  const float spx = sposS[bs * 2 + 0], spy = sposS[bs * 2 + 1];
  const float rx = 1.f / (sscaleS[bs * 2 + 0] * 5.f);
  const float ry = 1.f / (sscaleS[bs * 2 + 1] * 5.f);
  const float wpx = W_pos[lane], wpy = W_pos[64 + lane], bpv = b_pos[lane];
  const float gv = gln[lane], blnv = bln[lane];
  const float bb0 = b1[lane], bb1 = b1[lane + 64];
  const float b2qv = UPD ? 0.f : b2q[bs];
  float hacc0 = 0.f, hacc1 = 0.f;
  const size_t baseoff = (size_t)b * NPIX * 64;
  for (int it = 0; it < 8; ++it) {
    const int p0 = tile * 128 + wv * 32 + it * 4;
    float tv[4];
#pragma unroll
    for (int pp = 0; pp < 4; ++pp) {
      int p = p0 + pp;
      float gx = lin_(p & 63), gy = lin_(p >> 6);
      float grx = (gx - spx) * rx, gry = (gy - spy) * ry;
      float pe = grx * wpx + gry * wpy + bpv;
      tv[pp] = base[baseoff + (size_t)p * 64 + lane] + pe;
    }
    __syncthreads();
#pragma unroll
    for (int pp = 0; pp < 4; ++pp) {
      float m = wave_sum(tv[pp]) * 0.015625f;
      float c = tv[pp] - m;
      float var = wave_sum(c * c) * 0.015625f;
      tks[wv][pp][lane] = c * rsqrtf(var + 1e-5f) * gv + blnv;
    }
    __syncthreads();
    float a00 = bb0, a01 = bb1, a10 = bb0, a11 = bb1;
    float a20 = bb0, a21 = bb1, a30 = bb0, a31 = bb1;
#pragma unroll
    for (int d = 0; d < 64; ++d) {
      float2 wp = *(const float2*)&W1p[d * 128 + 2 * lane];
      float t0 = tks[wv][0][d], t1 = tks[wv][1][d];
      float t2 = tks[wv][2][d], t3 = tks[wv][3][d];
      a00 += t0 * wp.x; a01 += t0 * wp.y;
      a10 += t1 * wp.x; a11 += t1 * wp.y;
      a20 += t2 * wp.x; a21 += t2 * wp.y;
      a30 += t3 * wp.x; a31 += t3 * wp.y;
    }
    a00 = fmaxf(a00, 0.f); a01 = fmaxf(a01, 0.f);
    a10 = fmaxf(a10, 0.f); a11 = fmaxf(a11, 0.f);
    a20 = fmaxf(a20, 0.f); a21 = fmaxf(a21, 0.f);
    a30 = fmaxf(a30, 0.f); a31 = fmaxf(a31, 0.f);
    if (!UPD) {
      float wq0 = w2qs[lane], wq1 = w2qs[lane + 64];
      float s0 = wave_sum(a00 * wq0 + a01 * wq1);
      float s1 = wave_sum(a10 * wq0 + a11 * wq1);
      float s2 = wave_sum(a20 * wq0 + a21 * wq1);
      float s3 = wave_sum(a30 * wq0 + a31 * wq1);
      if (lane == 0) {
        dots[bs * NPIX + p0 + 0] = s0 + b2qv;
        dots[bs * NPIX + p0 + 1] = s1 + b2qv;
        dots[bs * NPIX + p0 + 2] = s2 + b2qv;
        dots[bs * NPIX + p0 + 3] = s3 + b2qv;
      }
    } else {
      float aw0 = attn[bs * NPIX + p0 + 0];
      float aw1 = attn[bs * NPIX + p0 + 1];
      float aw2 = attn[bs * NPIX + p0 + 2];
      float aw3 = attn[bs * NPIX + p0 + 3];
      hacc0 += aw0 * a00 + aw1 * a10 + aw2 * a20 + aw3 * a30;
      hacc1 += aw0 * a01 + aw1 * a11 + aw2 * a21 + aw3 * a31;
    }
  }
  if (UPD) {
    atomicAdd(&Hsum[bs * 128 + lane], hacc0);
    atomicAdd(&Hsum[bs * 128 + 64 + lane], hacc1);
  }
}

// ---------------- softmax over slot axis + moment accumulation ---------------
__global__ __launch_bounds__(256) void k_sm(const float* __restrict__ dots,
    float* __restrict__ attn, float* __restrict__ moments) {
  int idx = blockIdx.x * 256 + threadIdx.x;  // 0..32767 = B*N
  int b = idx >> 12, j = idx & 4095;
  int lane = threadIdx.x & 63;
  float dv[8];
  float mx = -1e30f;
#pragma unroll
  for (int s = 0; s < 8; ++s) {
    dv[s] = dots[(b * 8 + s) * NPIX + j] * 0.125f;
    mx = fmaxf(mx, dv[s]);
  }
  float tot = 0.f;
#pragma unroll
  for (int s = 0; s < 8; ++s) { dv[s] = expf(dv[s] - mx); tot += dv[s]; }
  float inv = 1.f / tot;
  float gx = lin_(j & 63), gy = lin_(j >> 6);
#pragma unroll
  for (int s = 0; s < 8; ++s) {
    float w = dv[s] * inv + 1e-8f;
    attn[(b * 8 + s) * NPIX + j] = w;
    float p0 = wave_sum(w);
    float p1 = wave_sum(w * gx);
    float p2 = wave_sum(w * gy);
    float p3 = wave_sum(w * gx * gx);
    float p4 = wave_sum(w * gy * gy);
    if (lane == 0) {
      float* mp = &moments[(b * 8 + s) * 5];
      atomicAdd(&mp[0], p0);
      atomicAdd(&mp[1], p1);
      atomicAdd(&mp[2], p2);
      atomicAdd(&mp[3], p3);
      atomicAdd(&mp[4], p4);
    }
  }
}

// ---------------- finalize: sp/ss, updates, GRU + FFN ------------------------
__global__ __launch_bounds__(192) void k_fin(
    const float* __restrict__ moments, const float* __restrict__ Hsum,
    const float* __restrict__ W2, const float* __restrict__ b2,
    const float* __restrict__ W_ih, const float* __restrict__ b_ih,
    const float* __restrict__ W_hh, const float* __restrict__ b_hh,
    const float* __restrict__ g_pre, const float* __restrict__ b_pre,
    const float* __restrict__ Wf1, const float* __restrict__ bf1,
    const float* __restrict__ Wf2, const float* __restrict__ bf2,
    float* __restrict__ slotsS, float* __restrict__ sposS, float* __restrict__ sscaleS,
    float* __restrict__ outSlots, float* __restrict__ outSpos,
    float* __restrict__ outSscale, int last) {
  const int bs = blockIdx.x;
  const int t = threadIdx.x;
  __shared__ float hsum_s[128], upd[64], sprev[64], xg[192], hg[192];
  __shared__ float snew[64], xpre[64], hf[128];
  const float M0 = moments[bs * 5 + 0];
  const float M1x = moments[bs * 5 + 1], M1y = moments[bs * 5 + 2];
  const float M2x = moments[bs * 5 + 3], M2y = moments[bs * 5 + 4];
  const float invM0 = 1.f / M0;
  const float spx = M1x * invM0, spy = M1y * invM0;
  const float M0a = M0 + 4096.f * 1e-8f;          // Sum(am), am = w + 1e-8
  const float G2 = 1408.6772487f * 1e-8f;          // 1e-8 * Sum_j grid[j,d]^2
  const float vx = (M2x + G2 - 2.f * spx * M1x + spx * spx * M0a) / M0a;
  const float vy = (M2y + G2 - 2.f * spy * M1y + spy * spy * M0a) / M0a;
  float ssx = sqrtf(fmaxf(vx, 0.f)), ssy = sqrtf(fmaxf(vy, 0.f));
  ssx = fminf(fmaxf(ssx, 0.001f), 2.f);
  ssy = fminf(fmaxf(ssy, 0.001f), 2.f);
  if (t == 0) {
    sposS[bs * 2 + 0] = spx; sposS[bs * 2 + 1] = spy;
    sscaleS[bs * 2 + 0] = ssx; sscaleS[bs * 2 + 1] = ssy;
    if (last) {
      outSpos[bs * 2 + 0] = spx; outSpos[bs * 2 + 1] = spy;
      outSscale[bs * 2 + 0] = ssx; outSscale[bs * 2 + 1] = ssy;
    }
  }
  if (last) {
    if (t < 64) outSlots[bs * 64 + t] = slotsS[bs * 64 + t];
    return;
  }
  if (t < 128) hsum_s[t] = Hsum[bs * 128 + t];
  if (t < 64) sprev[t] = slotsS[bs * 64 + t];
  __syncthreads();
  if (t < 64) {
    float a = 0.f;
#pragma unroll
    for (int k = 0; k < 128; ++k) a += hsum_s[k] * W2[k * 64 + t];
    upd[t] = a * invM0 + b2[t];
  }
  __syncthreads();
  {
    float a = b_ih[t], h = b_hh[t];
#pragma unroll
    for (int d = 0; d < 64; ++d) {
      a += upd[d] * W_ih[d * 192 + t];
      h += sprev[d] * W_hh[d * 192 + t];
    }
    xg[t] = a; hg[t] = h;
  }
  __syncthreads();
  if (t < 64) {
    float r = 1.f / (1.f + expf(-(xg[t] + hg[t])));
    float z = 1.f / (1.f + expf(-(xg[64 + t] + hg[64 + t])));
    float n = tanhf(xg[128 + t] + r * hg[128 + t]);
    snew[t] = (1.f - z) * n + z * sprev[t];
  }
  __syncthreads();
  if (t < 64) {
    float v = snew[t];
    float m = wave_sum(v) * 0.015625f;
    float c = v - m;
    float var = wave_sum(c * c) * 0.015625f;
    xpre[t] = c * rsqrtf(var + 1e-5f) * g_pre[t] + b_pre[t];
  }
  __syncthreads();
  if (t < 128) {
    float a = bf1[t];
#pragma unroll
    for (int d = 0; d < 64; ++d) a += xpre[d] * Wf1[d * 128 + t];
    hf[t] = fmaxf(a, 0.f);
  }
  __syncthreads();
  if (t < 64) {
    float a = bf2[t];
#pragma unroll
    for (int k = 0; k < 128; ++k) a += hf[k] * Wf2[k * 64 + t];
    slotsS[bs * 64 + t] = snew[t] + a;
  }
}

__global__ void k_zero(float* __restrict__ p, int n) {
  int i = blockIdx.x * 256 + threadIdx.x;
  if (i < n) p[i] = 0.f;
}

extern "C" void kernel_launch(void* const* d_in, const int* in_sizes, int n_in,
                              void* d_out, int out_size, void* d_ws, size_t ws_size,
                              hipStream_t stream) {
  const float* const* in = (const float* const*)d_in;
  float* ws = (float*)d_ws;
  // ws layout (float offsets)
  float* k0      = ws + 0;         // 2097152
  float* v0      = ws + 2097152;   // 2097152
  float* dots    = ws + 4194304;   // 262144
  float* w2qg    = ws + 4456448;   // 8192
  float* b2qg    = ws + 4464640;   // 64
  float* slotsS  = ws + 4464704;   // 4096
  float* sposS   = ws + 4468800;   // 128
  float* sscaleS = ws + 4468928;   // 128
  float* moments = ws + 4469056;   // 320
  float* Hsum    = ws + 4469376;   // 8192

  float* out = (float*)d_out;
  float* outSlots  = out;          // 4096
  float* outSpos   = out + 4096;   // 128
  float* outSscale = out + 4224;   // 128
  float* outAttn   = out + 4352;   // 262144

  k_init<<<16, 256, 0, stream>>>(in[1], in[2], in[3], slotsS, sposS, sscaleS);
  k_pre<<<8192, 256, 0, stream>>>(in[0], in[12], in[13], in[8], in[9], in[10], in[11], k0, v0);
  for (int i = 0; i < 4; ++i) {
    int last = (i == 3) ? 1 : 0;
    k_zero<<<34, 256, 0, stream>>>(moments, 8512);  // zeroes moments + Hsum (adjacent)
    k_q<<<64, 128, 0, stream>>>(slotsS, in[14], in[15], in[6], in[7], in[22], in[23], w2qg, b2qg);
    proj_pass<false><<<dim3(64, 32), 256, 0, stream>>>(
        k0, in[4], in[5], in[16], in[17], in[20], in[21],
        w2qg, b2qg, nullptr, nullptr, sposS, sscaleS, dots);
    k_sm<<<128, 256, 0, stream>>>(dots, outAttn, moments);
    if (!last) {
      proj_pass<true><<<dim3(64, 32), 256, 0, stream>>>(
          v0, in[4], in[5], in[18], in[19], in[20], in[21],
          nullptr, nullptr, outAttn, Hsum, sposS, sscaleS, nullptr);
    }
    k_fin<<<64, 192, 0, stream>>>(moments, Hsum, in[22], in[23], in[24], in[25],
                                  in[26], in[27], in[28], in[29], in[30], in[31],
                                  in[32], in[33], slotsS, sposS, sscaleS,
                                  outSlots, outSpos, outSscale, last);
  }
}

// Round 2
// 521.065 us; speedup vs baseline: 2.1906x; 2.1906x over previous
//
#include <hip/hip_runtime.h>
#include <math.h>

#define NPIX 4096

typedef __bf16 bf16_t;
typedef __bf16 bfrag __attribute__((ext_vector_type(8)));
typedef float ffrag __attribute__((ext_vector_type(4)));

__device__ __forceinline__ float wave_sum(float v) {
#pragma unroll
  for (int m = 32; m >= 1; m >>= 1) v += __shfl_xor(v, m, 64);
  return v;
}

__device__ __forceinline__ float lin_(int i) { return -1.f + (2.f * (float)i) / 63.f; }

// ---------------- init: broadcast slots_p, clip s_pos/s_scale, zero accum ----
__global__ __launch_bounds__(256) void k_init(const float* __restrict__ slots_p,
    const float* __restrict__ s_pos_p, const float* __restrict__ s_scale_p,
    float* __restrict__ slotsS, float* __restrict__ sposS, float* __restrict__ sscaleS,
    float* __restrict__ momentsHsum) {
  int i = blockIdx.x * 256 + threadIdx.x;
  if (i < 8 * 8 * 64) slotsS[i] = slots_p[i & 511];
  if (i < 8 * 8 * 2) {
    float p = s_pos_p[i & 15];
    sposS[i] = fminf(fmaxf(p, -1.f), 1.f);
    float sc = s_scale_p[i & 15];
    sscaleS[i] = fminf(fmaxf(sc, 0.001f), 2.f);
  }
  if (i < 8512) momentsHsum[i] = 0.f;  // moments(320) + Hsum(8192) contiguous
}

// ---------------- precompute: x = ln(inputs); k0 = x@Wk+bk; v0 = x@Wv+bv ----
__global__ __launch_bounds__(256) void k_pre(const float* __restrict__ inp,
    const float* __restrict__ g_in, const float* __restrict__ b_in,
    const float* __restrict__ Wk, const float* __restrict__ bk,
    const float* __restrict__ Wv, const float* __restrict__ bv,
    float* __restrict__ k0, float* __restrict__ v0) {
  int w = threadIdx.x >> 6, lane = threadIdx.x & 63;
  int p = blockIdx.x * 4 + w;  // 0..32767 = B*N
  float v = inp[(size_t)p * 64 + lane];
  float m = wave_sum(v) * 0.015625f;
  float c = v - m;
  float var = wave_sum(c * c) * 0.015625f;
  float x = c * rsqrtf(var + 1e-5f) * g_in[lane] + b_in[lane];
  __shared__ float xs[4][64];
  xs[w][lane] = x;
  __syncthreads();
  float ak = bk[lane], av = bv[lane];
#pragma unroll
  for (int d = 0; d < 64; ++d) {
    float xv = xs[w][d];
    ak += xv * Wk[d * 64 + lane];
    av += xv * Wv[d * 64 + lane];
  }
  k0[(size_t)p * 64 + lane] = ak;
  v0[(size_t)p * 64 + lane] = av;
}

// ---------------- once: fold LN gains into W1, transpose to [n][k] bf16 -----
__global__ __launch_bounds__(128) void k_wprep(
    const float* __restrict__ W1, const float* __restrict__ b1,
    const float* __restrict__ g_k, const float* __restrict__ b_k,
    const float* __restrict__ g_v, const float* __restrict__ b_v,
    bf16_t* __restrict__ W1kT, bf16_t* __restrict__ W1vT,
    float* __restrict__ u_k, float* __restrict__ u_v,
    float* __restrict__ w1s_k, float* __restrict__ w1s_v) {
  int n = threadIdx.x;  // 0..127
  float uk = 0.f, uv = 0.f, sk = 0.f, sv = 0.f;
  for (int c = 0; c < 64; ++c) {
    float w = W1[c * 128 + n];
    float wk = g_k[c] * w, wv = g_v[c] * w;
    W1kT[n * 64 + c] = (bf16_t)wk;
    W1vT[n * 64 + c] = (bf16_t)wv;
    sk += wk; sv += wv;
    uk += b_k[c] * w; uv += b_v[c] * w;
  }
  u_k[n] = uk + b1[n];
  u_v[n] = uv + b1[n];
  w1s_k[n] = sk;
  w1s_v[n] = sv;
}

// ---------------- initial q: q = ln(slots)@Wq+bq ; w2q = W2@q ; b2q = b2.q ---
__global__ __launch_bounds__(128) void k_q(
    const float* __restrict__ slotsS, const float* __restrict__ g_slots,
    const float* __restrict__ b_slots, const float* __restrict__ Wq,
    const float* __restrict__ bq, const float* __restrict__ W2,
    const float* __restrict__ b2, float* __restrict__ w2qg, float* __restrict__ b2qg) {
  const int bs = blockIdx.x;
  const int t = threadIdx.x;
  __shared__ float xn[64], qsh[64];
  if (t < 64) {
    float v = slotsS[bs * 64 + t];
    float m = wave_sum(v) * 0.015625f;
    float c = v - m;
    float var = wave_sum(c * c) * 0.015625f;
    xn[t] = c * rsqrtf(var + 1e-5f) * g_slots[t] + b_slots[t];
  }
  __syncthreads();
  if (t < 64) {
    float a = bq[t];
#pragma unroll
    for (int d = 0; d < 64; ++d) a += xn[d] * Wq[d * 64 + t];
    qsh[t] = a;
  }
  __syncthreads();
  {
    float a = 0.f;
#pragma unroll
    for (int d = 0; d < 64; ++d) a += W2[t * 64 + d] * qsh[d];
    w2qg[bs * 128 + t] = a;
  }
  if (t < 64) {
    float p = wave_sum(b2[t] * qsh[t]);
    if (t == 0) b2qg[bs] = p;
  }
}

// ---------------- MFMA proj pass (kk->dots, or vv->Hsum) ---------------------
// block: 256 thr (4 waves), one (b,s), 128 pixels. LN folded into epilogue.
template <bool UPD>
__global__ __launch_bounds__(256) void proj_mfma(
    const float* __restrict__ base, const float* __restrict__ W_pos,
    const float* __restrict__ b_pos, const bf16_t* __restrict__ W1T,
    const float* __restrict__ uvec, const float* __restrict__ w1s,
    const float* __restrict__ w2q, const float* __restrict__ b2q,
    const float* __restrict__ attn, float* __restrict__ Hsum,
    const float* __restrict__ sposS, const float* __restrict__ sscaleS,
    float* __restrict__ dots) {
  __shared__ bf16_t W1s[128][72];   // [n][k], stride 144B (16B-aligned, 2-way banks)
  __shared__ bf16_t Tsh[128][72];   // [pixel][k]
  __shared__ float rowr[128], rowmr[128];
  __shared__ float us[128], wsl[128], aux[128];
  __shared__ float wsum[4][128];
  const int bs = blockIdx.x;        // b*8+s
  const int tile = blockIdx.y;      // 0..31 (128 pixels each)
  const int tid = threadIdx.x;
  const int wv = tid >> 6, lane = tid & 63;
  const int lq = lane >> 4, ln15 = lane & 15;

  // stage W1T (128x64 bf16) into LDS
  for (int i = tid; i < 1024; i += 256) {
    int n = i >> 3, c8 = i & 7;
    *(uint4*)&W1s[n][c8 * 8] = *(const uint4*)&W1T[n * 64 + c8 * 8];
  }
  if (tid < 128) {
    us[tid] = uvec[tid];
    wsl[tid] = w1s[tid];
    aux[tid] = UPD ? attn[bs * NPIX + tile * 128 + tid] : w2q[bs * 128 + tid];
  }

  // phase A: T = base + pe  -> bf16 LDS (raw, LN folded into epilogue)
  const float spx = sposS[bs * 2 + 0], spy = sposS[bs * 2 + 1];
  const float rx = 1.f / (sscaleS[bs * 2 + 0] * 5.f);
  const float ry = 1.f / (sscaleS[bs * 2 + 1] * 5.f);
  const float wpx = W_pos[lane], wpy = W_pos[64 + lane], bpv = b_pos[lane];
  const size_t baseoff = (size_t)(bs >> 3) * NPIX * 64;
#pragma unroll 4
  for (int pl = wv * 32; pl < wv * 32 + 32; ++pl) {
    int P = tile * 128 + pl;
    float gx = lin_(P & 63), gy = lin_(P >> 6);
    float t = base[baseoff + (size_t)P * 64 + lane]
            + ((gx - spx) * rx) * wpx + ((gy - spy) * ry) * wpy + bpv;
    Tsh[pl][lane] = (bf16_t)t;
  }
  __syncthreads();

  // phase B: per-pixel LN stats from bf16 row (one lane per pixel)
  if (tid < 128) {
    float s = 0.f, s2 = 0.f;
#pragma unroll
    for (int j = 0; j < 8; ++j) {
      bfrag v = *(const bfrag*)&Tsh[tid][j * 8];
#pragma unroll
      for (int e = 0; e < 8; ++e) { float f = (float)v[e]; s += f; s2 += f * f; }
    }
    float m = s * 0.015625f;
    float var = s2 * 0.015625f - m * m;
    float r = rsqrtf(var + 1e-5f);
    rowr[tid] = r;
    rowmr[tid] = m * r;
  }
  __syncthreads();

  // MFMA phase: wave wv handles pixel rows [wv*32, wv*32+32) as 2 subtiles
  bfrag a[2][2];
#pragma unroll
  for (int s = 0; s < 2; ++s)
#pragma unroll
    for (int k = 0; k < 2; ++k)
      a[s][k] = *(const bfrag*)&Tsh[wv * 32 + s * 16 + ln15][k * 32 + lq * 8];
  float rr[2][4], mr[2][4], av[2][4];
#pragma unroll
  for (int s = 0; s < 2; ++s)
#pragma unroll
    for (int rg = 0; rg < 4; ++rg) {
      int row = wv * 32 + s * 16 + lq * 4 + rg;
      rr[s][rg] = rowr[row];
      mr[s][rg] = rowmr[row];
      av[s][rg] = UPD ? aux[row] : 0.f;
    }
  float dotacc[2][4] = {{0.f,0.f,0.f,0.f},{0.f,0.f,0.f,0.f}};
  float hpart[8] = {0.f,0.f,0.f,0.f,0.f,0.f,0.f,0.f};
  for (int nt = 0; nt < 8; ++nt) {
    bfrag b0 = *(const bfrag*)&W1s[nt * 16 + ln15][lq * 8];
    bfrag b1 = *(const bfrag*)&W1s[nt * 16 + ln15][32 + lq * 8];
    float un = us[nt * 16 + ln15];
    float wsn = wsl[nt * 16 + ln15];
    float wqn = UPD ? 0.f : aux[nt * 16 + ln15];
#pragma unroll
    for (int s = 0; s < 2; ++s) {
      ffrag c = {0.f, 0.f, 0.f, 0.f};
      c = __builtin_amdgcn_mfma_f32_16x16x32_bf16(a[s][0], b0, c, 0, 0, 0);
      c = __builtin_amdgcn_mfma_f32_16x16x32_bf16(a[s][1], b1, c, 0, 0, 0);
#pragma unroll
      for (int rg = 0; rg < 4; ++rg) {
        float h = fmaxf(rr[s][rg] * c[rg] + (un - mr[s][rg] * wsn), 0.f);
        if (!UPD) dotacc[s][rg] += h * wqn;
        else      hpart[nt] += av[s][rg] * h;
      }
    }
  }

  if (!UPD) {
    // reduce over n (lane bits 0..3), write dots
#pragma unroll
    for (int s = 0; s < 2; ++s)
#pragma unroll
      for (int rg = 0; rg < 4; ++rg) {
        float v = dotacc[s][rg];
        v += __shfl_xor(v, 1, 64);
        v += __shfl_xor(v, 2, 64);
        v += __shfl_xor(v, 4, 64);
        v += __shfl_xor(v, 8, 64);
        dotacc[s][rg] = v;
      }
    if (ln15 == 0) {
      float bq = b2q[bs];
#pragma unroll
      for (int s = 0; s < 2; ++s)
#pragma unroll
        for (int rg = 0; rg < 4; ++rg) {
          int P = tile * 128 + wv * 32 + s * 16 + lq * 4 + rg;
          dots[bs * NPIX + P] = dotacc[s][rg] + bq;
        }
    }
  } else {
    // reduce over quads (lane bits 4..5), then block-reduce, one atomic per n
#pragma unroll
    for (int nt = 0; nt < 8; ++nt) {
      float v = hpart[nt];
      v += __shfl_xor(v, 16, 64);
      v += __shfl_xor(v, 32, 64);
      hpart[nt] = v;
    }
    if (lane < 16) {
#pragma unroll
      for (int nt = 0; nt < 8; ++nt) wsum[wv][nt * 16 + lane] = hpart[nt];
    }
    __syncthreads();
    if (tid < 128) {
      float s = wsum[0][tid] + wsum[1][tid] + wsum[2][tid] + wsum[3][tid];
      atomicAdd(&Hsum[bs * 128 + tid], s);
    }
  }
}

// ---------------- softmax over slot axis + moment accumulation ---------------
__global__ __launch_bounds__(256) void k_sm(const float* __restrict__ dots,
    float* __restrict__ attn, float* __restrict__ moments) {
  int idx = blockIdx.x * 256 + threadIdx.x;  // 0..32767 = B*N
  int b = idx >> 12, j = idx & 4095;
  int lane = threadIdx.x & 63;
  float dv[8];
  float mx = -1e30f;
#pragma unroll
  for (int s = 0; s < 8; ++s) {
    dv[s] = dots[(b * 8 + s) * NPIX + j] * 0.125f;
    mx = fmaxf(mx, dv[s]);
  }
  float tot = 0.f;
#pragma unroll
  for (int s = 0; s < 8; ++s) { dv[s] = expf(dv[s] - mx); tot += dv[s]; }
  float inv = 1.f / tot;
  float gx = lin_(j & 63), gy = lin_(j >> 6);
#pragma unroll
  for (int s = 0; s < 8; ++s) {
    float w = dv[s] * inv + 1e-8f;
    attn[(b * 8 + s) * NPIX + j] = w;
    float p0 = wave_sum(w);
    float p1 = wave_sum(w * gx);
    float p2 = wave_sum(w * gy);
    float p3 = wave_sum(w * gx * gx);
    float p4 = wave_sum(w * gy * gy);
    if (lane == 0) {
      float* mp = &moments[(b * 8 + s) * 5];
      atomicAdd(&mp[0], p0);
      atomicAdd(&mp[1], p1);
      atomicAdd(&mp[2], p2);
      atomicAdd(&mp[3], p3);
      atomicAdd(&mp[4], p4);
    }
  }
}

// -------- finalize: sp/ss, updates, GRU + FFN, then next-iter q + zeroing ----
__global__ __launch_bounds__(192) void k_fin(
    float* __restrict__ moments, float* __restrict__ Hsum,
    const float* __restrict__ W2, const float* __restrict__ b2,
    const float* __restrict__ W_ih, const float* __restrict__ b_ih,
    const float* __restrict__ W_hh, const float* __restrict__ b_hh,
    const float* __restrict__ g_pre, const float* __restrict__ b_pre,
    const float* __restrict__ Wf1, const float* __restrict__ bf1,
    const float* __restrict__ Wf2, const float* __restrict__ bf2,
    const float* __restrict__ g_slots, const float* __restrict__ b_slots,
    const float* __restrict__ Wq, const float* __restrict__ bq,
    float* __restrict__ slotsS, float* __restrict__ sposS, float* __restrict__ sscaleS,
    float* __restrict__ w2qg, float* __restrict__ b2qg,
    float* __restrict__ outSlots, float* __restrict__ outSpos,
    float* __restrict__ outSscale, int last) {
  const int bs = blockIdx.x;
  const int t = threadIdx.x;
  __shared__ float hsum_s[128], upd[64], sprev[64], xg[192], hg[192];
  __shared__ float snew[64], xpre[64], hf[128], sfin[64], xn[64], qsh[64];
  const float M0 = moments[bs * 5 + 0];
  const float M1x = moments[bs * 5 + 1], M1y = moments[bs * 5 + 2];
  const float M2x = moments[bs * 5 + 3], M2y = moments[bs * 5 + 4];
  const float invM0 = 1.f / M0;
  const float spx = M1x * invM0, spy = M1y * invM0;
  const float M0a = M0 + 4096.f * 1e-8f;          // Sum(am), am = w + 1e-8
  const float G2 = 1408.6772487f * 1e-8f;          // 1e-8 * Sum_j grid[j,d]^2
  const float vx = (M2x + G2 - 2.f * spx * M1x + spx * spx * M0a) / M0a;
  const float vy = (M2y + G2 - 2.f * spy * M1y + spy * spy * M0a) / M0a;
  float ssx = sqrtf(fmaxf(vx, 0.f)), ssy = sqrtf(fmaxf(vy, 0.f));
  ssx = fminf(fmaxf(ssx, 0.001f), 2.f);
  ssy = fminf(fmaxf(ssy, 0.001f), 2.f);
  if (t == 0) {
    sposS[bs * 2 + 0] = spx; sposS[bs * 2 + 1] = spy;
    sscaleS[bs * 2 + 0] = ssx; sscaleS[bs * 2 + 1] = ssy;
    if (last) {
      outSpos[bs * 2 + 0] = spx; outSpos[bs * 2 + 1] = spy;
      outSscale[bs * 2 + 0] = ssx; outSscale[bs * 2 + 1] = ssy;
    }
  }
  if (last) {
    if (t < 64) outSlots[bs * 64 + t] = slotsS[bs * 64 + t];
    return;
  }
  if (t < 128) hsum_s[t] = Hsum[bs * 128 + t];
  if (t < 64) sprev[t] = slotsS[bs * 64 + t];
  __syncthreads();
  // zero accumulators for next iteration (values already consumed)
  if (t < 128) Hsum[bs * 128 + t] = 0.f;
  if (t < 5) moments[bs * 5 + t] = 0.f;
  if (t < 64) {
    float a = 0.f;
#pragma unroll
    for (int k = 0; k < 128; ++k) a += hsum_s[k] * W2[k * 64 + t];
    upd[t] = a * invM0 + b2[t];
  }
  __syncthreads();
  {
    float a = b_ih[t], h = b_hh[t];
#pragma unroll
    for (int d = 0; d < 64; ++d) {
      a += upd[d] * W_ih[d * 192 + t];
      h += sprev[d] * W_hh[d * 192 + t];
    }
    xg[t] = a; hg[t] = h;
  }
  __syncthreads();
  if (t < 64) {
    float r = 1.f / (1.f + expf(-(xg[t] + hg[t])));
    float z = 1.f / (1.f + expf(-(xg[64 + t] + hg[64 + t])));
    float n = tanhf(xg[128 + t] + r * hg[128 + t]);
    snew[t] = (1.f - z) * n + z * sprev[t];
  }
  __syncthreads();
  if (t < 64) {
    float v = snew[t];
    float m = wave_sum(v) * 0.015625f;
    float c = v - m;
    float var = wave_sum(c * c) * 0.015625f;
    xpre[t] = c * rsqrtf(var + 1e-5f) * g_pre[t] + b_pre[t];
  }
  __syncthreads();
  if (t < 128) {
    float a = bf1[t];
#pragma unroll
    for (int d = 0; d < 64; ++d) a += xpre[d] * Wf1[d * 128 + t];
    hf[t] = fmaxf(a, 0.f);
  }
  __syncthreads();
  if (t < 64) {
    float a = bf2[t];
#pragma unroll
    for (int k = 0; k < 128; ++k) a += hf[k] * Wf2[k * 64 + t];
    float nv = snew[t] + a;
    slotsS[bs * 64 + t] = nv;
    sfin[t] = nv;
  }
  __syncthreads();
  // ---- next-iteration q: ln(slots)@Wq+bq ; w2q = W2@q ; b2q = b2.q ----
  if (t < 64) {
    float v = sfin[t];
    float m = wave_sum(v) * 0.015625f;
    float c = v - m;
    float var = wave_sum(c * c) * 0.015625f;
    xn[t] = c * rsqrtf(var + 1e-5f) * g_slots[t] + b_slots[t];
  }
  __syncthreads();
  if (t < 64) {
    float a = bq[t];
#pragma unroll
    for (int d = 0; d < 64; ++d) a += xn[d] * Wq[d * 64 + t];
    qsh[t] = a;
  }
  __syncthreads();
  if (t < 128) {
    float a = 0.f;
#pragma unroll
    for (int d = 0; d < 64; ++d) a += W2[t * 64 + d] * qsh[d];
    w2qg[bs * 128 + t] = a;
  }
  if (t < 64) {
    float p = wave_sum(b2[t] * qsh[t]);
    if (t == 0) b2qg[bs] = p;
  }
}

extern "C" void kernel_launch(void* const* d_in, const int* in_sizes, int n_in,
                              void* d_out, int out_size, void* d_ws, size_t ws_size,
                              hipStream_t stream) {
  const float* const* in = (const float* const*)d_in;
  float* ws = (float*)d_ws;
  // ws layout (float offsets)
  float* k0      = ws + 0;         // 2097152
  float* v0      = ws + 2097152;   // 2097152
  float* dots    = ws + 4194304;   // 262144
  float* w2qg    = ws + 4456448;   // 8192
  float* b2qg    = ws + 4464640;   // 64
  float* slotsS  = ws + 4464704;   // 4096
  float* sposS   = ws + 4468800;   // 128
  float* sscaleS = ws + 4468928;   // 128
  float* moments = ws + 4469056;   // 320
  float* Hsum    = ws + 4469376;   // 8192
  bf16_t* W1kT   = (bf16_t*)(ws + 4477568);  // 8192 bf16 = 4096 floats
  bf16_t* W1vT   = (bf16_t*)(ws + 4481664);  // 8192 bf16
  float* u_k     = ws + 4485760;   // 128
  float* u_v     = ws + 4485888;   // 128
  float* w1s_k   = ws + 4486016;   // 128
  float* w1s_v   = ws + 4486144;   // 128

  float* out = (float*)d_out;
  float* outSlots  = out;          // 4096
  float* outSpos   = out + 4096;   // 128
  float* outSscale = out + 4224;   // 128
  float* outAttn   = out + 4352;   // 262144

  k_init<<<34, 256, 0, stream>>>(in[1], in[2], in[3], slotsS, sposS, sscaleS, moments);
  k_pre<<<8192, 256, 0, stream>>>(in[0], in[12], in[13], in[8], in[9], in[10], in[11], k0, v0);
  k_wprep<<<1, 128, 0, stream>>>(in[20], in[21], in[16], in[17], in[18], in[19],
                                 W1kT, W1vT, u_k, u_v, w1s_k, w1s_v);
  k_q<<<64, 128, 0, stream>>>(slotsS, in[14], in[15], in[6], in[7], in[22], in[23], w2qg, b2qg);
  for (int i = 0; i < 4; ++i) {
    int last = (i == 3) ? 1 : 0;
    proj_mfma<false><<<dim3(64, 32), 256, 0, stream>>>(
        k0, in[4], in[5], W1kT, u_k, w1s_k,
        w2qg, b2qg, nullptr, nullptr, sposS, sscaleS, dots);
    k_sm<<<128, 256, 0, stream>>>(dots, outAttn, moments);
    if (!last) {
      proj_mfma<true><<<dim3(64, 32), 256, 0, stream>>>(
          v0, in[4], in[5], W1vT, u_v, w1s_v,
          nullptr, nullptr, outAttn, Hsum, sposS, sscaleS, nullptr);
    }
    k_fin<<<64, 192, 0, stream>>>(moments, Hsum, in[22], in[23], in[24], in[25],
                                  in[26], in[27], in[28], in[29], in[30], in[31],
                                  in[32], in[33], in[14], in[15], in[6], in[7],
                                  slotsS, sposS, sscaleS, w2qg, b2qg,
                                  outSlots, outSpos, outSscale, last);
  }
}

// Round 3
// 296.479 us; speedup vs baseline: 3.8500x; 1.7575x over previous
//
#include <hip/hip_runtime.h>
#include <math.h>

typedef __bf16 bf16_t;
typedef __bf16 bfrag __attribute__((ext_vector_type(8)));
typedef float ffrag __attribute__((ext_vector_type(4)));

__device__ __forceinline__ float wave_sum(float v) {
#pragma unroll
  for (int m = 32; m >= 1; m >>= 1) v += __shfl_xor(v, m, 64);
  return v;
}
__device__ __forceinline__ float lin_(int i) { return -1.f + (2.f * (float)i) / 63.f; }
__device__ __forceinline__ float bflo(unsigned u) { return __uint_as_float(u << 16); }
__device__ __forceinline__ float bfhi(unsigned u) { return __uint_as_float(u & 0xFFFF0000u); }

// ============ setup: init state, fold LN gains into W1/Wk transposes =========
__global__ __launch_bounds__(256) void k_setup(
    const float* __restrict__ slots_p, const float* __restrict__ s_pos_p,
    const float* __restrict__ s_scale_p, const float* __restrict__ W1,
    const float* __restrict__ b1, const float* __restrict__ g_k,
    const float* __restrict__ b_k, const float* __restrict__ g_v,
    const float* __restrict__ b_v, const float* __restrict__ W_pos,
    const float* __restrict__ b_pos, const float* __restrict__ Wk,
    const float* __restrict__ Wv,
    float* __restrict__ slotsS, float* __restrict__ sposS,
    float* __restrict__ sscaleS, float* __restrict__ momentsHsum,
    bf16_t* __restrict__ W1kT, bf16_t* __restrict__ W1vT,
    bf16_t* __restrict__ WkT, bf16_t* __restrict__ WvT,
    float4* __restrict__ nckA, float* __restrict__ nckB,
    float4* __restrict__ ncvA, float* __restrict__ ncvB,
    float* __restrict__ possum) {
  int t = threadIdx.x;
  for (int i = t; i < 8512; i += 256) momentsHsum[i] = 0.f;
  for (int i = t; i < 4096; i += 256) slotsS[i] = slots_p[i & 511];
  if (t < 128) {
    sposS[t] = fminf(fmaxf(s_pos_p[t & 15], -1.f), 1.f);
    sscaleS[t] = fminf(fmaxf(s_scale_p[t & 15], 0.001f), 2.f);
  }
  for (int i = t; i < 4096; i += 256) {
    int n = i >> 6, d = i & 63;
    WkT[i] = (bf16_t)Wk[d * 64 + n];
    WvT[i] = (bf16_t)Wv[d * 64 + n];
  }
  if (t < 128) {
    int n = t;
    float wxk = 0, wyk = 0, wbk = 0, uk = 0, sk = 0;
    float wxv = 0, wyv = 0, wbv = 0, uv = 0, sv = 0;
    for (int c = 0; c < 64; ++c) {
      float w = W1[c * 128 + n];
      float wk = g_k[c] * w, wv = g_v[c] * w;
      W1kT[n * 64 + c] = (bf16_t)wk;
      W1vT[n * 64 + c] = (bf16_t)wv;
      float px = W_pos[c], py = W_pos[64 + c], bp = b_pos[c];
      wxk += px * wk; wyk += py * wk; wbk += bp * wk; sk += wk; uk += b_k[c] * w;
      wxv += px * wv; wyv += py * wv; wbv += bp * wv; sv += wv; uv += b_v[c] * w;
    }
    nckA[n] = make_float4(wxk, wyk, wbk, uk + b1[n]); nckB[n] = sk;
    ncvA[n] = make_float4(wxv, wyv, wbv, uv + b1[n]); ncvB[n] = sv;
  }
  if (t < 64) {
    float px = W_pos[t], py = W_pos[64 + t], bp = b_pos[t];
    float s[9] = {px, py, bp, px * px, py * py, bp * bp, px * py, px * bp, py * bp};
#pragma unroll
    for (int i = 0; i < 9; ++i) {
      float v = wave_sum(s[i]);
      if (t == 0) possum[i] = v;
    }
  }
}

// ============ k_pre: LN(inp) -> k0/v0 -> stats + P0 = t0 @ G1 (MFMA) =========
__device__ __forceinline__ void pass_type(
    const bf16_t xs[][72], bf16_t t0s[][72],
    const bf16_t WTl[][72], const bf16_t W1l[][72],
    const float* __restrict__ bias, const float* wpxs, const float* wpys,
    const float* bpvs, float* __restrict__ statsG, bf16_t* __restrict__ P0G,
    int j0, int wv, int lq, int ln15) {
  ffrag C[4] = {{0,0,0,0},{0,0,0,0},{0,0,0,0},{0,0,0,0}};
#pragma unroll
  for (int ks = 0; ks < 2; ++ks) {
    bfrag a = *(const bfrag*)&xs[wv * 16 + ln15][ks * 32 + lq * 8];
#pragma unroll
    for (int nt = 0; nt < 4; ++nt) {
      bfrag bb = *(const bfrag*)&WTl[nt * 16 + ln15][ks * 32 + lq * 8];
      C[nt] = __builtin_amdgcn_mfma_f32_16x16x32_bf16(a, bb, C[nt], 0, 0, 0);
    }
  }
  float kv[4][4];
  float st[5][4];
#pragma unroll
  for (int i = 0; i < 5; ++i)
#pragma unroll
    for (int rg = 0; rg < 4; ++rg) st[i][rg] = 0.f;
#pragma unroll
  for (int nt = 0; nt < 4; ++nt) {
    int n = nt * 16 + ln15;
    float bn = bias[n], pxw = wpxs[n], pyw = wpys[n], bpw = bpvs[n];
#pragma unroll
    for (int rg = 0; rg < 4; ++rg) {
      float v = C[nt][rg] + bn;
      kv[nt][rg] = v;
      st[0][rg] += v; st[1][rg] += v * v; st[2][rg] += v * pxw;
      st[3][rg] += v * pyw; st[4][rg] += v * bpw;
    }
  }
#pragma unroll
  for (int i = 0; i < 5; ++i)
#pragma unroll
    for (int rg = 0; rg < 4; ++rg) {
      float v = st[i][rg];
      v += __shfl_xor(v, 1, 64); v += __shfl_xor(v, 2, 64);
      v += __shfl_xor(v, 4, 64); v += __shfl_xor(v, 8, 64);
      st[i][rg] = v;
    }
  if (ln15 == 0) {
#pragma unroll
    for (int rg = 0; rg < 4; ++rg) {
      int j = j0 + wv * 16 + lq * 4 + rg;
#pragma unroll
      for (int i = 0; i < 5; ++i) statsG[j * 5 + i] = st[i][rg];
    }
  }
#pragma unroll
  for (int nt = 0; nt < 4; ++nt)
#pragma unroll
    for (int rg = 0; rg < 4; ++rg)
      t0s[wv * 16 + lq * 4 + rg][nt * 16 + ln15] = (bf16_t)kv[nt][rg];
  ffrag D[8] = {{0,0,0,0},{0,0,0,0},{0,0,0,0},{0,0,0,0},
                {0,0,0,0},{0,0,0,0},{0,0,0,0},{0,0,0,0}};
#pragma unroll
  for (int ks = 0; ks < 2; ++ks) {
    bfrag a = *(const bfrag*)&t0s[wv * 16 + ln15][ks * 32 + lq * 8];
#pragma unroll
    for (int nt = 0; nt < 8; ++nt) {
      bfrag bb = *(const bfrag*)&W1l[nt * 16 + ln15][ks * 32 + lq * 8];
      D[nt] = __builtin_amdgcn_mfma_f32_16x16x32_bf16(a, bb, D[nt], 0, 0, 0);
    }
  }
#pragma unroll
  for (int nt = 0; nt < 8; ++nt)
#pragma unroll
    for (int rg = 0; rg < 4; ++rg)
      P0G[(size_t)(j0 + wv * 16 + lq * 4 + rg) * 128 + nt * 16 + ln15] =
          (bf16_t)D[nt][rg];
}

__global__ __launch_bounds__(256) void k_pre(
    const float* __restrict__ inp, const float* __restrict__ g_in,
    const float* __restrict__ b_in, const float* __restrict__ bk,
    const float* __restrict__ bv, const bf16_t* __restrict__ WkT,
    const bf16_t* __restrict__ WvT, const bf16_t* __restrict__ W1kT,
    const bf16_t* __restrict__ W1vT, const float* __restrict__ W_pos,
    const float* __restrict__ b_pos,
    bf16_t* __restrict__ P0k, bf16_t* __restrict__ P0v,
    float* __restrict__ statsK, float* __restrict__ statsV,
    const float* __restrict__ slotsS, const float* __restrict__ g_slots,
    const float* __restrict__ b_slots, const float* __restrict__ Wq,
    const float* __restrict__ bq, const float* __restrict__ W2,
    const float* __restrict__ b2, float* __restrict__ w2qg,
    float* __restrict__ b2qg) {
  __shared__ bf16_t xs[64][72];
  __shared__ bf16_t t0s[64][72];
  __shared__ bf16_t WkTl[64][72];
  __shared__ bf16_t WvTl[64][72];
  __shared__ bf16_t W1kl[128][72];
  __shared__ bf16_t W1vl[128][72];
  __shared__ float wpxs[64], wpys[64], bpvs[64];
  const int tid = threadIdx.x;
  const int j0 = blockIdx.x * 64;
  for (int i = tid; i < 512; i += 256) {
    int row = i >> 3, seg = i & 7;
    *(uint4*)&WkTl[row][seg * 8] = ((const uint4*)WkT)[i];
    *(uint4*)&WvTl[row][seg * 8] = ((const uint4*)WvT)[i];
  }
  for (int i = tid; i < 1024; i += 256) {
    int row = i >> 3, seg = i & 7;
    *(uint4*)&W1kl[row][seg * 8] = ((const uint4*)W1kT)[i];
    *(uint4*)&W1vl[row][seg * 8] = ((const uint4*)W1vT)[i];
  }
  if (tid < 64) { wpxs[tid] = W_pos[tid]; wpys[tid] = W_pos[64 + tid]; bpvs[tid] = b_pos[tid]; }
  {
    const int px = tid >> 2, cg = tid & 3;
    const float* rowp = inp + (size_t)(j0 + px) * 64 + cg * 16;
    float v[16];
    *(float4*)&v[0]  = ((const float4*)rowp)[0];
    *(float4*)&v[4]  = ((const float4*)rowp)[1];
    *(float4*)&v[8]  = ((const float4*)rowp)[2];
    *(float4*)&v[12] = ((const float4*)rowp)[3];
    float s = 0.f, s2 = 0.f;
#pragma unroll
    for (int i = 0; i < 16; ++i) { s += v[i]; s2 += v[i] * v[i]; }
    s += __shfl_xor(s, 1, 64); s += __shfl_xor(s, 2, 64);
    s2 += __shfl_xor(s2, 1, 64); s2 += __shfl_xor(s2, 2, 64);
    float m = s * 0.015625f;
    float r = rsqrtf(s2 * 0.015625f - m * m + 1e-5f);
    float g[16], bb[16];
    *(float4*)&g[0]  = ((const float4*)(g_in + cg * 16))[0];
    *(float4*)&g[4]  = ((const float4*)(g_in + cg * 16))[1];
    *(float4*)&g[8]  = ((const float4*)(g_in + cg * 16))[2];
    *(float4*)&g[12] = ((const float4*)(g_in + cg * 16))[3];
    *(float4*)&bb[0]  = ((const float4*)(b_in + cg * 16))[0];
    *(float4*)&bb[4]  = ((const float4*)(b_in + cg * 16))[1];
    *(float4*)&bb[8]  = ((const float4*)(b_in + cg * 16))[2];
    *(float4*)&bb[12] = ((const float4*)(b_in + cg * 16))[3];
#pragma unroll
    for (int e = 0; e < 8; ++e) {
      float x0 = (v[2 * e] - m) * r * g[2 * e] + bb[2 * e];
      float x1 = (v[2 * e + 1] - m) * r * g[2 * e + 1] + bb[2 * e + 1];
      union { unsigned u; bf16_t h[2]; } cv;
      cv.h[0] = (bf16_t)x0; cv.h[1] = (bf16_t)x1;
      *(unsigned*)&xs[px][cg * 16 + 2 * e] = cv.u;
    }
  }
  __syncthreads();
  const int wv = tid >> 6, lane = tid & 63, lq = lane >> 4, ln15 = lane & 15;
  pass_type(xs, t0s, WkTl, W1kl, bk, wpxs, wpys, bpvs, statsK, P0k, j0, wv, lq, ln15);
  pass_type(xs, t0s, WvTl, W1vl, bv, wpxs, wpys, bpvs, statsV, P0v, j0, wv, lq, ln15);
  // initial q / w2q / b2q (wave 0 of first 64 blocks)
  if (blockIdx.x < 64 && tid < 64) {
    int bs = blockIdx.x, d = tid;
    float v = slotsS[bs * 64 + d];
    float m = wave_sum(v) * 0.015625f;
    float c = v - m;
    float var = wave_sum(c * c) * 0.015625f;
    float xn = c * rsqrtf(var + 1e-5f) * g_slots[d] + b_slots[d];
    float q = bq[d];
    for (int cc = 0; cc < 64; ++cc) q = fmaf(__shfl(xn, cc, 64), Wq[cc * 64 + d], q);
    float w0 = 0.f, w1 = 0.f;
    for (int cc = 0; cc < 64; ++cc) {
      float qc = __shfl(q, cc, 64);
      w0 = fmaf(W2[d * 64 + cc], qc, w0);
      w1 = fmaf(W2[(64 + d) * 64 + cc], qc, w1);
    }
    w2qg[bs * 128 + d] = w0;
    w2qg[bs * 128 + 64 + d] = w1;
    float p = wave_sum(b2[d] * q);
    if (d == 0) b2qg[bs] = p;
  }
}

// ============ k_iter: dots(8 slots) -> softmax -> moments -> V-hidden sum ====
template <int LAST>
__global__ __launch_bounds__(256) void k_iter(
    const bf16_t* __restrict__ P0kg, const bf16_t* __restrict__ P0vg,
    const float* __restrict__ statsK, const float* __restrict__ statsV,
    const float4* __restrict__ nckA, const float* __restrict__ nckB,
    const float4* __restrict__ ncvA, const float* __restrict__ ncvB,
    const float* __restrict__ possum, const float* __restrict__ w2qg,
    const float* __restrict__ b2qg, const float* __restrict__ sposS,
    const float* __restrict__ sscaleS, float* __restrict__ moments,
    float* __restrict__ Hsum, float* __restrict__ outAttn) {
  __shared__ unsigned P0kl[64 * 65];
  __shared__ unsigned P0vl[64 * 65];
  __shared__ float4 nckAl[128];
  __shared__ float nckBl[128];
  __shared__ float w2qTl[128][8];
  __shared__ float4 scalV[64][9];
  __shared__ float attnS[64][10];
  __shared__ float HsumW[4][8][128];
  __shared__ float momAcc[8][5];
  const int tid = threadIdx.x;
  const int tile = blockIdx.x, b = blockIdx.y;
  const int jg0 = b * 4096 + tile * 64;
#pragma unroll
  for (int r = 0; r < 4; ++r) {
    int idx = tid + 256 * r;
    int row = idx >> 4, seg = idx & 15;
    uint4 v = ((const uint4*)P0kg)[(size_t)(jg0 + row) * 16 + seg];
    unsigned* dst = &P0kl[row * 65 + seg * 4];
    dst[0] = v.x; dst[1] = v.y; dst[2] = v.z; dst[3] = v.w;
    if (!LAST) {
      uint4 w = ((const uint4*)P0vg)[(size_t)(jg0 + row) * 16 + seg];
      unsigned* d2 = &P0vl[row * 65 + seg * 4];
      d2[0] = w.x; d2[1] = w.y; d2[2] = w.z; d2[3] = w.w;
    }
  }
  if (tid < 128) { nckAl[tid] = nckA[tid]; nckBl[tid] = nckB[tid]; }
#pragma unroll
  for (int r = 0; r < 4; ++r) {
    int idx = tid + 256 * r;
    int s = idx >> 7, n = idx & 127;
    w2qTl[n][s] = w2qg[(b * 8 + s) * 128 + n];
  }
  if (tid < 40) momAcc[tid / 5][tid % 5] = 0.f;
  float4 ncv0 = {0, 0, 0, 0}, ncv1 = {0, 0, 0, 0};
  float wsv0 = 0.f, wsv1 = 0.f;
  if (!LAST) {
    int l = tid & 63;
    ncv0 = ncvA[l]; ncv1 = ncvA[l + 64];
    wsv0 = ncvB[l]; wsv1 = ncvB[l + 64];
  }
  __syncthreads();

  // ---- phase 1: dots for all 8 slots (k-range split over 4 lanes/pixel) ----
  const int px = tid >> 2, sp = tid & 3;
  const int jimg = tile * 64 + px;
  const float gx = lin_(jimg & 63), gy = lin_(jimg >> 6);
  const float Swx = possum[0], Swy = possum[1], Sbp = possum[2];
  const float Swx2 = possum[3], Swy2 = possum[4], Sbp2 = possum[5];
  const float Swxy = possum[6], Swxb = possum[7], Swyb = possum[8];
  float skA[5], svA[5];
#pragma unroll
  for (int i = 0; i < 5; ++i) {
    skA[i] = statsK[(size_t)(jg0 + px) * 5 + i];
    svA[i] = statsV[(size_t)(jg0 + px) * 5 + i];
  }
  float c1a[8], c2a[8], rKa[8], mrKa[8];
#pragma unroll
  for (int s = 0; s < 8; ++s) {
    int bs = b * 8 + s;
    float spx = sposS[bs * 2], spy = sposS[bs * 2 + 1];
    float rxx = 1.f / (sscaleS[bs * 2] * 5.f);
    float ryy = 1.f / (sscaleS[bs * 2 + 1] * 5.f);
    float c1 = (gx - spx) * rxx, c2 = (gy - spy) * ryy;
    float quad = c1 * c1 * Swx2 + c2 * c2 * Swy2 + Sbp2 +
                 2.f * (c1 * c2 * Swxy + c1 * Swxb + c2 * Swyb);
    float mK = (skA[0] + c1 * Swx + c2 * Swy + Sbp) * 0.015625f;
    float e2K = (skA[1] + 2.f * (c1 * skA[2] + c2 * skA[3] + skA[4]) + quad) * 0.015625f;
    float rK = rsqrtf(e2K - mK * mK + 1e-5f);
    c1a[s] = c1; c2a[s] = c2; rKa[s] = rK; mrKa[s] = mK * rK;
    if (!LAST && (s >> 1) == sp) {
      float mV = (svA[0] + c1 * Swx + c2 * Swy + Sbp) * 0.015625f;
      float e2V = (svA[1] + 2.f * (c1 * svA[2] + c2 * svA[3] + svA[4]) + quad) * 0.015625f;
      float rV = rsqrtf(e2V - mV * mV + 1e-5f);
      scalV[px][s] = make_float4(c1, c2, rV, mV * rV);
    }
  }
  float d8[8] = {0, 0, 0, 0, 0, 0, 0, 0};
#pragma unroll 4
  for (int i = 0; i < 16; ++i) {
    int k = sp * 16 + i;
    unsigned u = P0kl[px * 65 + k];
    float p0 = bflo(u), p1 = bfhi(u);
    float4 A0 = nckAl[2 * k], A1 = nckAl[2 * k + 1];
    float ws0 = nckBl[2 * k], ws1 = nckBl[2 * k + 1];
    float4 q0a = *(const float4*)&w2qTl[2 * k][0];
    float4 q0b = *(const float4*)&w2qTl[2 * k][4];
    float4 q1a = *(const float4*)&w2qTl[2 * k + 1][0];
    float4 q1b = *(const float4*)&w2qTl[2 * k + 1][4];
    float qq0[8] = {q0a.x, q0a.y, q0a.z, q0a.w, q0b.x, q0b.y, q0b.z, q0b.w};
    float qq1[8] = {q1a.x, q1a.y, q1a.z, q1a.w, q1b.x, q1b.y, q1b.z, q1b.w};
    float bm0 = p0 + A0.z, bm1 = p1 + A1.z;
#pragma unroll
    for (int s = 0; s < 8; ++s) {
      float z0 = bm0 + c1a[s] * A0.x + c2a[s] * A0.y;
      float h0 = fmaxf(fmaf(rKa[s], z0, fmaf(-mrKa[s], ws0, A0.w)), 0.f);
      d8[s] = fmaf(h0, qq0[s], d8[s]);
      float z1 = bm1 + c1a[s] * A1.x + c2a[s] * A1.y;
      float h1 = fmaxf(fmaf(rKa[s], z1, fmaf(-mrKa[s], ws1, A1.w)), 0.f);
      d8[s] = fmaf(h1, qq1[s], d8[s]);
    }
  }
#pragma unroll
  for (int s = 0; s < 8; ++s) {
    float v = d8[s];
    v += __shfl_xor(v, 1, 64);
    v += __shfl_xor(v, 2, 64);
    d8[s] = (v + b2qg[b * 8 + s]) * 0.125f;
  }
  float mx = d8[0];
#pragma unroll
  for (int s = 1; s < 8; ++s) mx = fmaxf(mx, d8[s]);
  float tt = 0.f;
  float e8[8];
#pragma unroll
  for (int s = 0; s < 8; ++s) { e8[s] = expf(d8[s] - mx); tt += e8[s]; }
  float inv = 1.f / tt;
#pragma unroll
  for (int s = 0; s < 8; ++s) e8[s] = e8[s] * inv + 1e-8f;
  float wa, wb;
  if (sp == 0) { wa = e8[0]; wb = e8[1]; }
  else if (sp == 1) { wa = e8[2]; wb = e8[3]; }
  else if (sp == 2) { wa = e8[4]; wb = e8[5]; }
  else { wa = e8[6]; wb = e8[7]; }
  *(float2*)&attnS[px][sp * 2] = make_float2(wa, wb);
  if (LAST) {
    outAttn[(size_t)(b * 8 + sp * 2) * 4096 + jimg] = wa;
    outAttn[(size_t)(b * 8 + sp * 2 + 1) * 4096 + jimg] = wb;
  }
  {
    float mm[10] = {wa, wa * gx, wa * gy, wa * gx * gx, wa * gy * gy,
                    wb, wb * gx, wb * gy, wb * gx * gx, wb * gy * gy};
#pragma unroll
    for (int i = 0; i < 10; ++i) {
      float v = mm[i];
      v += __shfl_xor(v, 4, 64); v += __shfl_xor(v, 8, 64);
      v += __shfl_xor(v, 16, 64); v += __shfl_xor(v, 32, 64);
      mm[i] = v;
    }
    if ((tid & 63) < 4) {
#pragma unroll
      for (int i = 0; i < 5; ++i) {
        atomicAdd(&momAcc[sp * 2][i], mm[i]);
        atomicAdd(&momAcc[sp * 2 + 1][i], mm[5 + i]);
      }
    }
  }
  __syncthreads();

  // ---- phase 2: Hsum += attn * relu(V hidden) --------------------------------
  if (!LAST) {
    const int w = tid >> 6, l = tid & 63;
    float hacc[8][2];
#pragma unroll
    for (int s = 0; s < 8; ++s) { hacc[s][0] = 0.f; hacc[s][1] = 0.f; }
    const unsigned short* P16 = (const unsigned short*)P0vl;
#pragma unroll 2
    for (int i = 0; i < 16; ++i) {
      int j = w * 16 + i;
      float pv0 = __uint_as_float((unsigned)P16[j * 130 + l] << 16);
      float pv1 = __uint_as_float((unsigned)P16[j * 130 + 64 + l] << 16);
      float bm0 = pv0 + ncv0.z, bm1 = pv1 + ncv1.z;
#pragma unroll
      for (int s = 0; s < 8; ++s) {
        float4 sc = scalV[j][s];
        float aw = attnS[j][s];
        float z0 = bm0 + sc.x * ncv0.x + sc.y * ncv0.y;
        float h0 = fmaxf(fmaf(sc.z, z0, fmaf(-sc.w, wsv0, ncv0.w)), 0.f);
        hacc[s][0] = fmaf(aw, h0, hacc[s][0]);
        float z1 = bm1 + sc.x * ncv1.x + sc.y * ncv1.y;
        float h1 = fmaxf(fmaf(sc.z, z1, fmaf(-sc.w, wsv1, ncv1.w)), 0.f);
        hacc[s][1] = fmaf(aw, h1, hacc[s][1]);
      }
    }
#pragma unroll
    for (int s = 0; s < 8; ++s) {
      HsumW[w][s][l] = hacc[s][0];
      HsumW[w][s][l + 64] = hacc[s][1];
    }
    __syncthreads();
#pragma unroll
    for (int r = 0; r < 4; ++r) {
      int i = tid + 256 * r;
      int s = i >> 7, n = i & 127;
      float v = HsumW[0][s][n] + HsumW[1][s][n] + HsumW[2][s][n] + HsumW[3][s][n];
      atomicAdd(&Hsum[(b * 8 + s) * 128 + n], v);
    }
  }
  if (tid < 40)
    atomicAdd(&moments[(b * 8 + tid / 5) * 5 + tid % 5], momAcc[tid / 5][tid % 5]);
}

// ============ finalize: sp/ss, GRU + FFN, next-iter q (unchanged, verified) ==
__global__ __launch_bounds__(192) void k_fin(
    float* __restrict__ moments, float* __restrict__ Hsum,
    const float* __restrict__ W2, const float* __restrict__ b2,
    const float* __restrict__ W_ih, const float* __restrict__ b_ih,
    const float* __restrict__ W_hh, const float* __restrict__ b_hh,
    const float* __restrict__ g_pre, const float* __restrict__ b_pre,
    const float* __restrict__ Wf1, const float* __restrict__ bf1,
    const float* __restrict__ Wf2, const float* __restrict__ bf2,
    const float* __restrict__ g_slots, const float* __restrict__ b_slots,
    const float* __restrict__ Wq, const float* __restrict__ bq,
    float* __restrict__ slotsS, float* __restrict__ sposS, float* __restrict__ sscaleS,
    float* __restrict__ w2qg, float* __restrict__ b2qg,
    float* __restrict__ outSlots, float* __restrict__ outSpos,
    float* __restrict__ outSscale, int last) {
  const int bs = blockIdx.x;
  const int t = threadIdx.x;
  __shared__ float hsum_s[128], upd[64], sprev[64], xg[192], hg[192];
  __shared__ float snew[64], xpre[64], hf[128], sfin[64], xn[64], qsh[64];
  const float M0 = moments[bs * 5 + 0];
  const float M1x = moments[bs * 5 + 1], M1y = moments[bs * 5 + 2];
  const float M2x = moments[bs * 5 + 3], M2y = moments[bs * 5 + 4];
  const float invM0 = 1.f / M0;
  const float spx = M1x * invM0, spy = M1y * invM0;
  const float M0a = M0 + 4096.f * 1e-8f;
  const float G2 = 1408.6772487f * 1e-8f;
  const float vx = (M2x + G2 - 2.f * spx * M1x + spx * spx * M0a) / M0a;
  const float vy = (M2y + G2 - 2.f * spy * M1y + spy * spy * M0a) / M0a;
  float ssx = sqrtf(fmaxf(vx, 0.f)), ssy = sqrtf(fmaxf(vy, 0.f));
  ssx = fminf(fmaxf(ssx, 0.001f), 2.f);
  ssy = fminf(fmaxf(ssy, 0.001f), 2.f);
  if (t == 0) {
    sposS[bs * 2 + 0] = spx; sposS[bs * 2 + 1] = spy;
    sscaleS[bs * 2 + 0] = ssx; sscaleS[bs * 2 + 1] = ssy;
    if (last) {
      outSpos[bs * 2 + 0] = spx; outSpos[bs * 2 + 1] = spy;
      outSscale[bs * 2 + 0] = ssx; outSscale[bs * 2 + 1] = ssy;
    }
  }
  if (last) {
    if (t < 64) outSlots[bs * 64 + t] = slotsS[bs * 64 + t];
    return;
  }
  if (t < 128) hsum_s[t] = Hsum[bs * 128 + t];
  if (t < 64) sprev[t] = slotsS[bs * 64 + t];
  __syncthreads();
  if (t < 128) Hsum[bs * 128 + t] = 0.f;
  if (t < 5) moments[bs * 5 + t] = 0.f;
  if (t < 64) {
    float a = 0.f;
#pragma unroll
    for (int k = 0; k < 128; ++k) a += hsum_s[k] * W2[k * 64 + t];
    upd[t] = a * invM0 + b2[t];
  }
  __syncthreads();
  {
    float a = b_ih[t], h = b_hh[t];
#pragma unroll
    for (int d = 0; d < 64; ++d) {
      a += upd[d] * W_ih[d * 192 + t];
      h += sprev[d] * W_hh[d * 192 + t];
    }
    xg[t] = a; hg[t] = h;
  }
  __syncthreads();
  if (t < 64) {
    float r = 1.f / (1.f + expf(-(xg[t] + hg[t])));
    float z = 1.f / (1.f + expf(-(xg[64 + t] + hg[64 + t])));
    float n = tanhf(xg[128 + t] + r * hg[128 + t]);
    snew[t] = (1.f - z) * n + z * sprev[t];
  }
  __syncthreads();
  if (t < 64) {
    float v = snew[t];
    float m = wave_sum(v) * 0.015625f;
    float c = v - m;
    float var = wave_sum(c * c) * 0.015625f;
    xpre[t] = c * rsqrtf(var + 1e-5f) * g_pre[t] + b_pre[t];
  }
  __syncthreads();
  if (t < 128) {
    float a = bf1[t];
#pragma unroll
    for (int d = 0; d < 64; ++d) a += xpre[d] * Wf1[d * 128 + t];
    hf[t] = fmaxf(a, 0.f);
  }
  __syncthreads();
  if (t < 64) {
    float a = bf2[t];
#pragma unroll
    for (int k = 0; k < 128; ++k) a += hf[k] * Wf2[k * 64 + t];
    float nv = snew[t] + a;
    slotsS[bs * 64 + t] = nv;
    sfin[t] = nv;
  }
  __syncthreads();
  if (t < 64) {
    float v = sfin[t];
    float m = wave_sum(v) * 0.015625f;
    float c = v - m;
    float var = wave_sum(c * c) * 0.015625f;
    xn[t] = c * rsqrtf(var + 1e-5f) * g_slots[t] + b_slots[t];
  }
  __syncthreads();
  if (t < 64) {
    float a = bq[t];
#pragma unroll
    for (int d = 0; d < 64; ++d) a += xn[d] * Wq[d * 64 + t];
    qsh[t] = a;
  }
  __syncthreads();
  if (t < 128) {
    float a = 0.f;
#pragma unroll
    for (int d = 0; d < 64; ++d) a += W2[t * 64 + d] * qsh[d];
    w2qg[bs * 128 + t] = a;
  }
  if (t < 64) {
    float p = wave_sum(b2[t] * qsh[t]);
    if (t == 0) b2qg[bs] = p;
  }
}

extern "C" void kernel_launch(void* const* d_in, const int* in_sizes, int n_in,
                              void* d_out, int out_size, void* d_ws, size_t ws_size,
                              hipStream_t stream) {
  const float* const* in = (const float* const*)d_in;
  float* ws = (float*)d_ws;
  bf16_t* P0k   = (bf16_t*)(ws + 0);        // 2,097,152 f32 slots (8 MB)
  bf16_t* P0v   = (bf16_t*)(ws + 2097152);  // 2,097,152
  float* statsK = ws + 4194304;             // 163,840
  float* statsV = ws + 4358144;             // 163,840
  float* w2qg   = ws + 4521984;             // 8192
  float* b2qg   = ws + 4530176;             // 64
  float* slotsS = ws + 4530240;             // 4096
  float* sposS  = ws + 4534336;             // 128
  float* sscaleS= ws + 4534464;             // 128
  float* moments= ws + 4534592;             // 320  (contiguous with Hsum: 8512)
  float* Hsum   = ws + 4534912;             // 8192
  bf16_t* W1kT  = (bf16_t*)(ws + 4543104);  // 4096 f32 slots
  bf16_t* W1vT  = (bf16_t*)(ws + 4547200);  // 4096
  bf16_t* WkT   = (bf16_t*)(ws + 4551296);  // 2048
  bf16_t* WvT   = (bf16_t*)(ws + 4553344);  // 2048
  float4* nckA  = (float4*)(ws + 4555392);  // 512
  float* nckB   = ws + 4555904;             // 128
  float4* ncvA  = (float4*)(ws + 4556032);  // 512
  float* ncvB   = ws + 4556544;             // 128
  float* possum = ws + 4556672;             // 9

  float* out = (float*)d_out;
  float* outSlots  = out;
  float* outSpos   = out + 4096;
  float* outSscale = out + 4224;
  float* outAttn   = out + 4352;

  k_setup<<<1, 256, 0, stream>>>(in[1], in[2], in[3], in[20], in[21],
                                 in[16], in[17], in[18], in[19], in[4], in[5],
                                 in[8], in[10], slotsS, sposS, sscaleS, moments,
                                 W1kT, W1vT, WkT, WvT, nckA, nckB, ncvA, ncvB, possum);
  k_pre<<<512, 256, 0, stream>>>(in[0], in[12], in[13], in[9], in[11],
                                 WkT, WvT, W1kT, W1vT, in[4], in[5],
                                 P0k, P0v, statsK, statsV,
                                 slotsS, in[14], in[15], in[6], in[7], in[22], in[23],
                                 w2qg, b2qg);
  for (int i = 0; i < 4; ++i) {
    int last = (i == 3) ? 1 : 0;
    if (!last) {
      k_iter<0><<<dim3(64, 8), 256, 0, stream>>>(
          P0k, P0v, statsK, statsV, nckA, nckB, ncvA, ncvB, possum,
          w2qg, b2qg, sposS, sscaleS, moments, Hsum, outAttn);
    } else {
      k_iter<1><<<dim3(64, 8), 256, 0, stream>>>(
          P0k, P0v, statsK, statsV, nckA, nckB, ncvA, ncvB, possum,
          w2qg, b2qg, sposS, sscaleS, moments, Hsum, outAttn);
    }
    k_fin<<<64, 192, 0, stream>>>(moments, Hsum, in[22], in[23], in[24], in[25],
                                  in[26], in[27], in[28], in[29], in[30], in[31],
                                  in[32], in[33], in[14], in[15], in[6], in[7],
                                  slotsS, sposS, sscaleS, w2qg, b2qg,
                                  outSlots, outSpos, outSscale, last);
  }
}